// Round 4
// baseline (243.636 us; speedup 1.0000x reference)
//
#include <hip/hip_runtime.h>

#define Hh 8
#define HD 128
#define NEG_SLOPE 0.2f
#define EPC 2048   // edges per sort block (256 thr x 8)
#define GRS 197    // ghs row stride: 196 bucket run-starts + total count

// R3 post-mortem: preprocessing (138us) is latency-bound, ~9x off its 15us BW
// roofline. k_b2 = 1.5 waves/SIMD with serial returning-atomic chains; k_b3 =
// 0.77 waves/SIMD, two tmp passes. Fix: block-PRIVATE level-1 sort (packed
// word carries full dst since dst<65536, so each block sorts its 2048-edge
// chunk into its own tmp region; cursors are local LDS scans -> the global
// gh scan pipeline disappears), then k_csr with 4 sub-blocks per bucket.

// round-to-nearest-even fp32 -> bf16 (as uint16 in low bits)
__device__ __forceinline__ unsigned bfr(float f) {
    unsigned u = __float_as_uint(f);
    return (u + 0x7fffu + ((u >> 16) & 1u)) >> 16;
}
__device__ __forceinline__ unsigned pk(float a, float b) { return bfr(a) | (bfr(b) << 16); }

// Kernel A: blocks [0,nblk): private bucket sort of a 2048-edge chunk.
//   wbuf stash (uint4 LDS writes, conflict-free) -> LDS hist -> local scan ->
//   dump run-starts (ghs row, u16) + fire-forget bktcnt atomics -> place into
//   private tmp region (write-confined, no cross-block sharing).
// Blocks [nblk,..): ew + bf16 pack of h_src (co-scheduled BW/VALU waves).
__global__ void __launch_bounds__(256)
k_sort(const int* __restrict__ src, const int* __restrict__ dst,
       unsigned* __restrict__ tmp, unsigned short* __restrict__ ghs,
       int* __restrict__ bktcnt, int E, int nblk,
       const float* __restrict__ hs, const float* __restrict__ attn,
       float* __restrict__ ew, uint4* __restrict__ hsb, int nh_src) {
    int t = threadIdx.x;
    if ((int)blockIdx.x < nblk) {
        __shared__ unsigned wbuf[EPC];
        __shared__ int lh[256], cur[256];
        int blk = blockIdx.x;
        int base_e = blk * EPC;
        int cnt = E - base_e; if (cnt > EPC) cnt = EPC;
        lh[t] = 0;
        __syncthreads();
        int i = t * 8;
        if (i + 7 < cnt) {
            int4 d0 = *(const int4*)(dst + base_e + i);
            int4 d1 = *(const int4*)(dst + base_e + i + 4);
            int4 s0 = *(const int4*)(src + base_e + i);
            int4 s1 = *(const int4*)(src + base_e + i + 4);
            uint4 w0, w1;
            w0.x = ((unsigned)d0.x << 16) | (unsigned)s0.x;
            w0.y = ((unsigned)d0.y << 16) | (unsigned)s0.y;
            w0.z = ((unsigned)d0.z << 16) | (unsigned)s0.z;
            w0.w = ((unsigned)d0.w << 16) | (unsigned)s0.w;
            w1.x = ((unsigned)d1.x << 16) | (unsigned)s1.x;
            w1.y = ((unsigned)d1.y << 16) | (unsigned)s1.y;
            w1.z = ((unsigned)d1.z << 16) | (unsigned)s1.z;
            w1.w = ((unsigned)d1.w << 16) | (unsigned)s1.w;
            ((uint4*)wbuf)[(i >> 2)]     = w0;   // b128 LDS write: conflict-free
            ((uint4*)wbuf)[(i >> 2) + 1] = w1;
            atomicAdd(&lh[d0.x >> 8], 1);
            atomicAdd(&lh[d0.y >> 8], 1);
            atomicAdd(&lh[d0.z >> 8], 1);
            atomicAdd(&lh[d0.w >> 8], 1);
            atomicAdd(&lh[d1.x >> 8], 1);
            atomicAdd(&lh[d1.y >> 8], 1);
            atomicAdd(&lh[d1.z >> 8], 1);
            atomicAdd(&lh[d1.w >> 8], 1);
        } else {
            for (int e = i; e < cnt; ++e) {
                int d = dst[base_e + e];
                wbuf[e] = ((unsigned)d << 16) | (unsigned)src[base_e + e];
                atomicAdd(&lh[d >> 8], 1);
            }
        }
        __syncthreads();
        int v = lh[t];
        cur[t] = v;
        __syncthreads();
        for (int off = 1; off < 256; off <<= 1) {
            int x = (t >= off) ? cur[t - off] : 0;
            __syncthreads();
            cur[t] += x;
            __syncthreads();
        }
        int excl = cur[t] - v;   // exclusive run start within chunk
        if (t < GRS) ghs[(size_t)blk * GRS + t] = (unsigned short)excl;
        if (t < 196 && v) atomicAdd(&bktcnt[t], v);   // fire-and-forget
        cur[t] = excl;
        __syncthreads();
        if (i + 7 < cnt) {
            uint4 w0 = ((uint4*)wbuf)[(i >> 2)];
            uint4 w1 = ((uint4*)wbuf)[(i >> 2) + 1];
            unsigned wa[8] = {w0.x, w0.y, w0.z, w0.w, w1.x, w1.y, w1.z, w1.w};
#pragma unroll
            for (int k = 0; k < 8; ++k) {
                int p = atomicAdd(&cur[wa[k] >> 24], 1);   // w>>24 == dst>>8
                tmp[base_e + p] = wa[k];                   // private region
            }
        } else {
            for (int e = i; e < cnt; ++e) {
                unsigned w = wbuf[e];
                int p = atomicAdd(&cur[w >> 24], 1);
                tmp[base_e + p] = w;
            }
        }
    } else {
        int i = ((int)blockIdx.x - nblk) * 256 + t;
        if (i >= nh_src) return;
        int n = i >> 3, h = i & 7;
        const float4* a = (const float4*)(hs + (size_t)n * HD + h * 16);
        const float4* w = (const float4*)(attn + h * 16);
        float4 x0 = a[0], x1 = a[1], x2 = a[2], x3 = a[3];
        float4 w0 = w[0], w1 = w[1], w2 = w[2], w3 = w[3];
        float s = x0.x * w0.x + x0.y * w0.y + x0.z * w0.z + x0.w * w0.w
                + x1.x * w1.x + x1.y * w1.y + x1.z * w1.z + x1.w * w1.w
                + x2.x * w2.x + x2.y * w2.y + x2.z * w2.z + x2.w * w2.w
                + x3.x * w3.x + x3.y * w3.y + x3.z * w3.z + x3.w * w3.w;
        s = (s >= 0.f) ? s : NEG_SLOPE * s;
        ew[i] = __expf(s);   // no max-subtraction: |logit| <= ~25, exp finite in fp32
        uint4 p0 = { pk(x0.x, x0.y), pk(x0.z, x0.w), pk(x1.x, x1.y), pk(x1.z, x1.w) };
        uint4 p1 = { pk(x2.x, x2.y), pk(x2.z, x2.w), pk(x3.x, x3.y), pk(x3.z, x3.w) };
        hsb[(size_t)n * 16 + h * 2]     = p0;
        hsb[(size_t)n * 16 + h * 2 + 1] = p1;
    }
}

// Kernel B: 4 sub-blocks per bucket (bucket b = blockIdx>>2, sub s = &3).
// Each walks ALL source-blocks' runs for bucket b (ghs is L2-resident),
// builds per-sub LDS hist (non-returning atomics), redundantly scans bktcnt
// for the global bucket base, derives per-dst per-sub cursors locally, then
// places its own quarter. Scatter confined to the bucket's 16KB adj window.
__global__ void __launch_bounds__(256)
k_csr(const unsigned* __restrict__ tmp, const unsigned short* __restrict__ ghs,
      const int* __restrict__ bktcnt, unsigned short* __restrict__ adj,
      int* __restrict__ row_ptr, int E, int nblk, int nbkt, int ndst) {
    __shared__ int lh0[256], lh1[256], lh2[256], lh3[256];
    __shared__ int sc[256], cur[256];
    __shared__ int base_s;
    int t = threadIdx.x;
    int b = blockIdx.x >> 2;
    int s = blockIdx.x & 3;
    int Q = (nblk + 3) >> 2;
    lh0[t] = 0; lh1[t] = 0; lh2[t] = 0; lh3[t] = 0;
    __syncthreads();
    for (int blk = t; blk < nblk; blk += 256) {
        const unsigned short* gr = ghs + (size_t)blk * GRS;
        int st = gr[b], en = gr[b + 1];
        const unsigned* tp = tmp + (size_t)blk * EPC;
        int sub = blk / Q;
        int* lhp = (sub == 0) ? lh0 : (sub == 1) ? lh1 : (sub == 2) ? lh2 : lh3;
        for (int j = st; j < en; ++j)
            atomicAdd(&lhp[(tp[j] >> 16) & 255], 1);   // non-returning
    }
    __syncthreads();
    int l0 = lh0[t], l1 = lh1[t], l2 = lh2[t], l3 = lh3[t];
    int tot = l0 + l1 + l2 + l3;
    // bucket base: redundant exclusive scan of bktcnt (196 ints, L2-hot)
    int bc = (t < nbkt) ? bktcnt[t] : 0;
    sc[t] = bc;
    __syncthreads();
    for (int off = 1; off < 256; off <<= 1) {
        int x = (t >= off) ? sc[t - off] : 0;
        __syncthreads();
        sc[t] += x;
        __syncthreads();
    }
    if (t == b) base_s = sc[t] - bc;
    __syncthreads();
    int base_b = base_s;
    // per-dst exclusive scan of bucket-total degree
    sc[t] = tot;
    __syncthreads();
    for (int off = 1; off < 256; off <<= 1) {
        int x = (t >= off) ? sc[t - off] : 0;
        __syncthreads();
        sc[t] += x;
        __syncthreads();
    }
    int start = sc[t] - tot;
    int myoff = ((s > 0) ? l0 : 0) + ((s > 1) ? l1 : 0) + ((s > 2) ? l2 : 0);
    cur[t] = base_b + start + myoff;
    if (s == 0) {
        int d = b * 256 + t;
        if (d < ndst) row_ptr[d] = base_b + start;
        if (b == 0 && t == 0) row_ptr[ndst] = E;
    }
    __syncthreads();
    int Qs = s * Q, Qe = Qs + Q; if (Qe > nblk) Qe = nblk;
    for (int blk = Qs + t; blk < Qe; blk += 256) {
        const unsigned short* gr = ghs + (size_t)blk * GRS;
        int st = gr[b], en = gr[b + 1];
        const unsigned* tp = tmp + (size_t)blk * EPC;
        for (int j = st; j < en; ++j) {
            unsigned w = tp[j];
            int p = atomicAdd(&cur[(w >> 16) & 255], 1);
            adj[p] = (unsigned short)(w & 0xffff);
        }
    }
}

#define ACC8(X, W) \
    a0.x += __uint_as_float((X).x << 16) * (W); \
    a0.y += __uint_as_float((X).x & 0xffff0000u) * (W); \
    a0.z += __uint_as_float((X).y << 16) * (W); \
    a0.w += __uint_as_float((X).y & 0xffff0000u) * (W); \
    a1.x += __uint_as_float((X).z << 16) * (W); \
    a1.y += __uint_as_float((X).z & 0xffff0000u) * (W); \
    a1.z += __uint_as_float((X).w << 16) * (W); \
    a1.w += __uint_as_float((X).w & 0xffff0000u) * (W);

// one block (128 thr) per dst. bf16 row gather (256B rows, 16 lanes/row,
// 8 edge-slots, 4x unroll = 32 rows outstanding per block), fp32 accumulate.
__global__ void __launch_bounds__(128)
k_agg(const int* __restrict__ row_ptr, const unsigned short* __restrict__ adj,
      const uint4* __restrict__ hsb, const float* __restrict__ ew,
      float* __restrict__ out) {
    int d = blockIdx.x;
    int t = threadIdx.x;
    int j0 = row_ptr[d], j1 = row_ptr[d + 1];
    int q = t & 15;          // channels 8q..8q+7
    int slot = t >> 4;       // 8 edge-slots
    int h = q >> 1;

    float4 a0 = {0.f, 0.f, 0.f, 0.f}, a1 = {0.f, 0.f, 0.f, 0.f};
    float ws = 0.f;
    int j = j0 + slot;
    for (; j + 24 < j1; j += 32) {
        int s0 = adj[j], s1 = adj[j + 8], s2 = adj[j + 16], s3 = adj[j + 24];
        float w0 = ew[s0 * Hh + h], w1 = ew[s1 * Hh + h];
        float w2 = ew[s2 * Hh + h], w3 = ew[s3 * Hh + h];
        uint4 x0 = hsb[(size_t)s0 * 16 + q];
        uint4 x1 = hsb[(size_t)s1 * 16 + q];
        uint4 x2 = hsb[(size_t)s2 * 16 + q];
        uint4 x3 = hsb[(size_t)s3 * 16 + q];
        ACC8(x0, w0)
        ACC8(x1, w1)
        ACC8(x2, w2)
        ACC8(x3, w3)
        ws += w0 + w1 + w2 + w3;
    }
    for (; j < j1; j += 8) {
        int s0 = adj[j];
        float w0 = ew[s0 * Hh + h];
        uint4 x0 = hsb[(size_t)s0 * 16 + q];
        ACC8(x0, w0)
        ws += w0;
    }

#pragma unroll
    for (int off = 16; off <= 32; off <<= 1) {
        a0.x += __shfl_xor(a0.x, off, 64);
        a0.y += __shfl_xor(a0.y, off, 64);
        a0.z += __shfl_xor(a0.z, off, 64);
        a0.w += __shfl_xor(a0.w, off, 64);
        a1.x += __shfl_xor(a1.x, off, 64);
        a1.y += __shfl_xor(a1.y, off, 64);
        a1.z += __shfl_xor(a1.z, off, 64);
        a1.w += __shfl_xor(a1.w, off, 64);
        ws   += __shfl_xor(ws,   off, 64);
    }
    __shared__ float4 sp0[16], sp1[16];
    __shared__ float wsp[16];
    if (t >= 64 && t < 80) { sp0[q] = a0; sp1[q] = a1; wsp[q] = ws; }
    __syncthreads();
    if (t < 16) {
        float wt = ws + wsp[t];
        float r = (wt > 0.f) ? 1.0f / wt : 0.f;
        float4 o0 = sp0[t], o1 = sp1[t];
        o0.x = (a0.x + o0.x) * r; o0.y = (a0.y + o0.y) * r;
        o0.z = (a0.z + o0.z) * r; o0.w = (a0.w + o0.w) * r;
        o1.x = (a1.x + o1.x) * r; o1.y = (a1.y + o1.y) * r;
        o1.z = (a1.z + o1.z) * r; o1.w = (a1.w + o1.w) * r;
        float4* op = (float4*)(out + (size_t)d * HD + t * 8);
        op[0] = o0;
        op[1] = o1;
    }
}

extern "C" void kernel_launch(void* const* d_in, const int* in_sizes, int n_in,
                              void* d_out, int out_size, void* d_ws, size_t ws_size,
                              hipStream_t stream) {
    const float* h_src  = (const float*)d_in[0];
    const float* attn_l = (const float*)d_in[2];
    const int*   src    = (const int*)d_in[3];
    const int*   dst    = (const int*)d_in[4];
    float* out = (float*)d_out;

    const int N_src = in_sizes[0] / HD;
    const int N_dst = in_sizes[1] / HD;
    const int E     = in_sizes[3];
    const int NH_src = N_src * Hh;

    const int NBLK  = (E + EPC - 1) / EPC;       // sort blocks (782)
    const int NBKT  = (N_dst + 255) / 256;       // dst buckets (196)
    const int NB_EW = (NH_src + 255) / 256;

    // workspace layout; hsb first to keep 16B alignment (row = 256B)
    unsigned short* hsb = (unsigned short*)d_ws;            // N_src*128 bf16
    float* ew = (float*)(hsb + (size_t)N_src * HD);         // NH_src
    unsigned* tmp = (unsigned*)(ew + NH_src);               // E packed (dst<<16|src)
    int* row_ptr = (int*)(tmp + E);                         // N_dst+1
    int* bktcnt  = row_ptr + (N_dst + 1);                   // 256
    unsigned short* adj = (unsigned short*)(bktcnt + 256);  // E (src as u16)
    unsigned short* ghs = adj + (((size_t)E + 1) & ~(size_t)1);  // NBLK*197

    hipMemsetAsync(bktcnt, 0, 256 * sizeof(int), stream);
    k_sort<<<NBLK + NB_EW, 256, 0, stream>>>(src, dst, tmp, ghs, bktcnt, E, NBLK,
                                             h_src, attn_l, ew, (uint4*)hsb, NH_src);
    k_csr<<<NBKT * 4, 256, 0, stream>>>(tmp, ghs, bktcnt, adj, row_ptr,
                                        E, NBLK, NBKT, N_dst);
    k_agg<<<N_dst, 128, 0, stream>>>(row_ptr, adj, (const uint4*)hsb, ew, out);
}

// Round 5
// 194.514 us; speedup vs baseline: 1.2525x; 1.2525x over previous
//
#include <hip/hip_runtime.h>

#define Hh 8
#define HD 128
#define NEG_SLOPE 0.2f
#define EPB 4096   // edges per partition block (1024 thr x 4)

// R4 post-mortem: private-sort + k_csr regressed (4x tmp read amp, 4-way
// interleaved bucket-window writes = R1's line-bounce disease). Reverted to
// R3's two-level bucket sort. R3's remaining cost is occupancy: 391/196-block
// grids at 256 thr = 0.8-1.5 waves/SIMD, nothing hides LDS-atomic latency.
// This version keeps EPB=4096 (21-edge contiguous write runs in k_b2) but
// uses 1024-thr blocks: same grids, 16 waves/block = 4-6 waves/SIMD.

// round-to-nearest-even fp32 -> bf16 (as uint16 in low bits)
__device__ __forceinline__ unsigned bfr(float f) {
    unsigned u = __float_as_uint(f);
    return (u + 0x7fffu + ((u >> 16) & 1u)) >> 16;
}
__device__ __forceinline__ unsigned pk(float a, float b) { return bfr(a) | (bfr(b) << 16); }

// pass 1, fused. Blocks [0,nblk): per-block bucket histogram (bucket = dst>>8)
// via LDS atomics -> gh[bucket*nblk + blk]. Blocks [nblk,..): ew+bf16 copy
// (co-scheduled: VALU/BW waves overlap the LDS-atomic waves).
__global__ void __launch_bounds__(1024)
k_b1(const int* __restrict__ dst, int* __restrict__ gh,
     int E, int nblk, int nbkt,
     const float* __restrict__ hs, const float* __restrict__ attn,
     float* __restrict__ ew, uint4* __restrict__ hsb, int nh_src) {
    int t = threadIdx.x;
    if ((int)blockIdx.x < nblk) {
        __shared__ int lh[256];
        if (t < 256) lh[t] = 0;
        __syncthreads();
        int base = blockIdx.x * EPB;
        int cnt = E - base; if (cnt > EPB) cnt = EPB;
        int i = t * 4;
        if (i + 3 < cnt) {
            int4 d = *(const int4*)(dst + base + i);
            atomicAdd(&lh[d.x >> 8], 1);
            atomicAdd(&lh[d.y >> 8], 1);
            atomicAdd(&lh[d.z >> 8], 1);
            atomicAdd(&lh[d.w >> 8], 1);
        } else {
            // only the straddling thread iterates; others have i >= cnt
            for (int e = i; e < cnt; ++e) atomicAdd(&lh[dst[base + e] >> 8], 1);
        }
        __syncthreads();
        if (t < nbkt) gh[t * nblk + blockIdx.x] = lh[t];
    } else {
        int i = ((int)blockIdx.x - nblk) * 1024 + t;
        if (i >= nh_src) return;
        int n = i >> 3, h = i & 7;
        const float4* a = (const float4*)(hs + (size_t)n * HD + h * 16);
        const float4* w = (const float4*)(attn + h * 16);
        float4 x0 = a[0], x1 = a[1], x2 = a[2], x3 = a[3];
        float4 w0 = w[0], w1 = w[1], w2 = w[2], w3 = w[3];
        float s = x0.x * w0.x + x0.y * w0.y + x0.z * w0.z + x0.w * w0.w
                + x1.x * w1.x + x1.y * w1.y + x1.z * w1.z + x1.w * w1.w
                + x2.x * w2.x + x2.y * w2.y + x2.z * w2.z + x2.w * w2.w
                + x3.x * w3.x + x3.y * w3.y + x3.z * w3.z + x3.w * w3.w;
        s = (s >= 0.f) ? s : NEG_SLOPE * s;
        ew[i] = __expf(s);   // no max-subtraction: |logit| <= ~25, exp finite in fp32
        uint4 p0 = { pk(x0.x, x0.y), pk(x0.z, x0.w), pk(x1.x, x1.y), pk(x1.z, x1.w) };
        uint4 p1 = { pk(x2.x, x2.y), pk(x2.z, x2.w), pk(x3.x, x3.y), pk(x3.z, x3.w) };
        hsb[(size_t)n * 16 + h * 2]     = p0;
        hsb[(size_t)n * 16 + h * 2 + 1] = p1;
    }
}

// scan stage 1: per-256-chunk block sums of gh
__global__ void k_gsum(const int* __restrict__ g, int* __restrict__ partial, int n) {
    __shared__ int sh[256];
    int t = threadIdx.x;
    int i = blockIdx.x * 256 + t;
    sh[t] = (i < n) ? g[i] : 0;
    __syncthreads();
    for (int off = 128; off > 0; off >>= 1) {
        if (t < off) sh[t] += sh[t + off];
        __syncthreads();
    }
    if (t == 0) partial[blockIdx.x] = sh[0];
}

// scan stage 2 (merged): each block computes its own prefix over `partial`
// cooperatively (<= 2 reads/thread), then local exclusive scan of gh chunk.
__global__ void k_gscan(int* __restrict__ g, const int* __restrict__ partial, int n) {
    __shared__ int sh[256];
    __shared__ int pre_s;
    int t = threadIdx.x;
    int acc = 0;
    for (int k = t; k < (int)blockIdx.x; k += 256) acc += partial[k];
    sh[t] = acc;
    __syncthreads();
    for (int off = 128; off > 0; off >>= 1) {
        if (t < off) sh[t] += sh[t + off];
        __syncthreads();
    }
    if (t == 0) pre_s = sh[0];
    __syncthreads();
    int pre = pre_s;
    int i = blockIdx.x * 256 + t;
    int v = (i < n) ? g[i] : 0;
    __syncthreads();
    sh[t] = v;
    __syncthreads();
    for (int off = 1; off < 256; off <<= 1) {
        int x = (t >= off) ? sh[t - off] : 0;
        __syncthreads();
        sh[t] += x;
        __syncthreads();
    }
    if (i < n) g[i] = pre + sh[t] - v;  // exclusive
}

// pass 2: scatter edges into bucket segments. LDS cursors (returning LDS atomics),
// packed word = (dst&255)<<16 | src  (src < 65536 for this problem).
__global__ void __launch_bounds__(1024)
k_b2(const int* __restrict__ src, const int* __restrict__ dst,
     const int* __restrict__ gh, int* __restrict__ tmp,
     int E, int nblk, int nbkt) {
    __shared__ int cur[256];
    int t = threadIdx.x, blk = blockIdx.x;
    if (t < nbkt) cur[t] = gh[t * nblk + blk];
    __syncthreads();
    int base = blk * EPB;
    int cnt = E - base; if (cnt > EPB) cnt = EPB;
    int i = t * 4;
    if (i + 3 < cnt) {
        int4 d = *(const int4*)(dst + base + i);
        int4 s = *(const int4*)(src + base + i);
        int p;
        p = atomicAdd(&cur[d.x >> 8], 1); tmp[p] = ((d.x & 255) << 16) | s.x;
        p = atomicAdd(&cur[d.y >> 8], 1); tmp[p] = ((d.y & 255) << 16) | s.y;
        p = atomicAdd(&cur[d.z >> 8], 1); tmp[p] = ((d.z & 255) << 16) | s.z;
        p = atomicAdd(&cur[d.w >> 8], 1); tmp[p] = ((d.w & 255) << 16) | s.w;
    } else {
        for (int e = i; e < cnt; ++e) {
            int d = dst[base + e];
            int p = atomicAdd(&cur[d >> 8], 1);
            tmp[p] = ((d & 255) << 16) | src[base + e];
        }
    }
}

// pass 3: one block per bucket. LDS histogram of 256 local dst -> LDS scan ->
// row_ptr, then placement pass with LDS cursors -> adj (src only, u16).
// 1024 thr: histogram/placement stride 1024 (8 iters/thread), scan on t<256.
__global__ void __launch_bounds__(1024)
k_b3(const int* __restrict__ gh, const int* __restrict__ tmp,
     unsigned short* __restrict__ adj, int* __restrict__ row_ptr,
     int E, int nblk, int nbkt, int ndst) {
    __shared__ int lh[256], sh[256], cur[256];
    int b = blockIdx.x, t = threadIdx.x;
    int s0 = gh[b * nblk];
    int s1 = (b + 1 < nbkt) ? gh[(b + 1) * nblk] : E;
    if (t < 256) lh[t] = 0;
    __syncthreads();
    for (int j = s0 + t; j < s1; j += 1024)
        atomicAdd(&lh[tmp[j] >> 16], 1);
    __syncthreads();
    int v = 0;
    if (t < 256) { v = lh[t]; sh[t] = v; }
    __syncthreads();
    for (int off = 1; off < 256; off <<= 1) {
        int x = 0;
        if (t < 256 && t >= off) x = sh[t - off];
        __syncthreads();
        if (t < 256) sh[t] += x;
        __syncthreads();
    }
    if (t < 256) {
        int start = s0 + sh[t] - v;   // exclusive
        cur[t] = start;
        int d = b * 256 + t;
        if (d < ndst) row_ptr[d] = start;
        if (b == nbkt - 1 && t == 0) row_ptr[ndst] = E;
    }
    __syncthreads();
    for (int j = s0 + t; j < s1; j += 1024) {
        int w = tmp[j];
        int pos = atomicAdd(&cur[w >> 16], 1);
        adj[pos] = (unsigned short)(w & 0xffff);
    }
}

#define ACC8(X, W) \
    a0.x += __uint_as_float((X).x << 16) * (W); \
    a0.y += __uint_as_float((X).x & 0xffff0000u) * (W); \
    a0.z += __uint_as_float((X).y << 16) * (W); \
    a0.w += __uint_as_float((X).y & 0xffff0000u) * (W); \
    a1.x += __uint_as_float((X).z << 16) * (W); \
    a1.y += __uint_as_float((X).z & 0xffff0000u) * (W); \
    a1.z += __uint_as_float((X).w << 16) * (W); \
    a1.w += __uint_as_float((X).w & 0xffff0000u) * (W);

// one block (128 thr) per dst. bf16 row gather (256B rows, 16 lanes/row,
// 8 edge-slots, 4x unroll = 32 rows outstanding per block), fp32 accumulate.
__global__ void __launch_bounds__(128)
k_agg(const int* __restrict__ row_ptr, const unsigned short* __restrict__ adj,
      const uint4* __restrict__ hsb, const float* __restrict__ ew,
      float* __restrict__ out) {
    int d = blockIdx.x;
    int t = threadIdx.x;
    int j0 = row_ptr[d], j1 = row_ptr[d + 1];
    int q = t & 15;          // channels 8q..8q+7
    int slot = t >> 4;       // 8 edge-slots
    int h = q >> 1;

    float4 a0 = {0.f, 0.f, 0.f, 0.f}, a1 = {0.f, 0.f, 0.f, 0.f};
    float ws = 0.f;
    int j = j0 + slot;
    for (; j + 24 < j1; j += 32) {
        int s0 = adj[j], s1 = adj[j + 8], s2 = adj[j + 16], s3 = adj[j + 24];
        float w0 = ew[s0 * Hh + h], w1 = ew[s1 * Hh + h];
        float w2 = ew[s2 * Hh + h], w3 = ew[s3 * Hh + h];
        uint4 x0 = hsb[(size_t)s0 * 16 + q];
        uint4 x1 = hsb[(size_t)s1 * 16 + q];
        uint4 x2 = hsb[(size_t)s2 * 16 + q];
        uint4 x3 = hsb[(size_t)s3 * 16 + q];
        ACC8(x0, w0)
        ACC8(x1, w1)
        ACC8(x2, w2)
        ACC8(x3, w3)
        ws += w0 + w1 + w2 + w3;
    }
    for (; j < j1; j += 8) {
        int s0 = adj[j];
        float w0 = ew[s0 * Hh + h];
        uint4 x0 = hsb[(size_t)s0 * 16 + q];
        ACC8(x0, w0)
        ws += w0;
    }

#pragma unroll
    for (int off = 16; off <= 32; off <<= 1) {
        a0.x += __shfl_xor(a0.x, off, 64);
        a0.y += __shfl_xor(a0.y, off, 64);
        a0.z += __shfl_xor(a0.z, off, 64);
        a0.w += __shfl_xor(a0.w, off, 64);
        a1.x += __shfl_xor(a1.x, off, 64);
        a1.y += __shfl_xor(a1.y, off, 64);
        a1.z += __shfl_xor(a1.z, off, 64);
        a1.w += __shfl_xor(a1.w, off, 64);
        ws   += __shfl_xor(ws,   off, 64);
    }
    __shared__ float4 sp0[16], sp1[16];
    __shared__ float wsp[16];
    if (t >= 64 && t < 80) { sp0[q] = a0; sp1[q] = a1; wsp[q] = ws; }
    __syncthreads();
    if (t < 16) {
        float wt = ws + wsp[t];
        float r = (wt > 0.f) ? 1.0f / wt : 0.f;
        float4 o0 = sp0[t], o1 = sp1[t];
        o0.x = (a0.x + o0.x) * r; o0.y = (a0.y + o0.y) * r;
        o0.z = (a0.z + o0.z) * r; o0.w = (a0.w + o0.w) * r;
        o1.x = (a1.x + o1.x) * r; o1.y = (a1.y + o1.y) * r;
        o1.z = (a1.z + o1.z) * r; o1.w = (a1.w + o1.w) * r;
        float4* op = (float4*)(out + (size_t)d * HD + t * 8);
        op[0] = o0;
        op[1] = o1;
    }
}

extern "C" void kernel_launch(void* const* d_in, const int* in_sizes, int n_in,
                              void* d_out, int out_size, void* d_ws, size_t ws_size,
                              hipStream_t stream) {
    const float* h_src  = (const float*)d_in[0];
    const float* attn_l = (const float*)d_in[2];
    const int*   src    = (const int*)d_in[3];
    const int*   dst    = (const int*)d_in[4];
    float* out = (float*)d_out;

    const int N_src = in_sizes[0] / HD;
    const int N_dst = in_sizes[1] / HD;
    const int E     = in_sizes[3];
    const int NH_src = N_src * Hh;

    const int NBLK = (E + EPB - 1) / EPB;        // edge partition blocks (391)
    const int NBKT = (N_dst + 255) / 256;        // dst buckets (196)
    const int M    = NBKT * NBLK;                // gh length (~77K)
    const int NC   = (M + 255) / 256;            // scan chunks (~300)
    const int NB_EW = (NH_src + 1023) / 1024;    // ew blocks (391)

    // workspace layout; hsb first to keep 16B alignment (row = 256B)
    unsigned short* hsb = (unsigned short*)d_ws;            // N_src*128 bf16
    float* ew      = (float*)(hsb + (size_t)N_src * HD);    // NH_src
    int*   tmp     = (int*)(ew + NH_src);                   // E packed (local<<16|src)
    unsigned short* adj = (unsigned short*)(tmp + E);       // E (src as u16)
    int*   gh      = (int*)(adj + (((size_t)E + 1) & ~(size_t)1)); // M
    int*   partial = gh + M;                                // NC
    int*   row_ptr = partial + NC;                          // N_dst+1

    k_b1<<<NBLK + NB_EW, 1024, 0, stream>>>(dst, gh, E, NBLK, NBKT,
                                            h_src, attn_l, ew, (uint4*)hsb, NH_src);
    k_gsum <<<NC, 256, 0, stream>>>(gh, partial, M);
    k_gscan<<<NC, 256, 0, stream>>>(gh, partial, M);
    k_b2<<<NBLK, 1024, 0, stream>>>(src, dst, gh, tmp, E, NBLK, NBKT);
    k_b3<<<NBKT, 1024, 0, stream>>>(gh, tmp, adj, row_ptr, E, NBLK, NBKT, N_dst);
    k_agg<<<N_dst, 128, 0, stream>>>(row_ptr, adj, (const uint4*)hsb, ew, out);
}